// Round 1
// baseline (1350.218 us; speedup 1.0000x reference)
//
#include <hip/hip_runtime.h>
#include <hip/hip_bf16.h>

#define N_NODES 50000
#define N_EDGES 800000
#define IN_FEAT 128
#define HIDDEN  256
#define OUT_F   64

// ---------------- degree count ----------------
__global__ void count_edges_k(const int* __restrict__ dst, int* __restrict__ cnt) {
    int e = blockIdx.x * blockDim.x + threadIdx.x;
    if (e < N_EDGES) atomicAdd(&cnt[dst[e]], 1);
}

// ---------------- scatter layer 1: agg1[dst] += x[src], 128 feats ----------------
__global__ void scatter1_k(const float* __restrict__ x, const int* __restrict__ src,
                           const int* __restrict__ dst, float* __restrict__ agg) {
    int e = blockIdx.x;           // one block per edge
    int t = threadIdx.x;          // 128 threads = feature
    int s = src[e], d = dst[e];
    atomicAdd(&agg[(size_t)d * IN_FEAT + t], x[(size_t)s * IN_FEAT + t]);
}

// ---------------- scatter layer 2: agg2[dst] += h[src], 256 feats ----------------
__global__ void scatter2_k(const float* __restrict__ h, const int* __restrict__ src,
                           const int* __restrict__ dst, float* __restrict__ agg) {
    int e = blockIdx.x;           // one block per edge
    int t = threadIdx.x;          // 256 threads = feature
    int s = src[e], d = dst[e];
    atomicAdd(&agg[(size_t)d * HIDDEN + t], h[(size_t)s * HIDDEN + t]);
}

// ---------------- W[R][C] -> WT[C][R] ----------------
__global__ void transpose_k(const float* __restrict__ W, float* __restrict__ WT,
                            int R, int C) {
    int i = blockIdx.x * blockDim.x + threadIdx.x;
    if (i < R * C) {
        int r = i / C, c = i % C;
        WT[c * R + r] = W[i];
    }
}

// ---------------- GEMM1: h = relu(aggm @ W1_l^T + b1 + x @ W1_r^T) ----------------
// 8 nodes per block, 256 threads (thread = output channel j)
__global__ void gemm1_k(const float* __restrict__ x, const float* __restrict__ agg,
                        const int* __restrict__ cnt,
                        const float* __restrict__ W1lT, const float* __restrict__ W1rT,
                        const float* __restrict__ b1, float* __restrict__ h) {
    __shared__ float xs[8][IN_FEAT];
    __shared__ float as[8][IN_FEAT];
    int nb = blockIdx.x * 8;
    int t = threadIdx.x;
    for (int i = t; i < 8 * IN_FEAT; i += 256) {
        int n = i / IN_FEAT, k = i % IN_FEAT;
        int node = nb + n;
        float xv = 0.f, av = 0.f;
        if (node < N_NODES) {
            xv = x[(size_t)node * IN_FEAT + k];
            int c = cnt[node]; if (c < 1) c = 1;
            av = agg[(size_t)node * IN_FEAT + k] / (float)c;
        }
        xs[n][k] = xv; as[n][k] = av;
    }
    __syncthreads();
    float acc[8];
#pragma unroll
    for (int n = 0; n < 8; n++) acc[n] = 0.f;
    for (int k = 0; k < IN_FEAT; k++) {
        float wl = W1lT[k * HIDDEN + t];
        float wr = W1rT[k * HIDDEN + t];
#pragma unroll
        for (int n = 0; n < 8; n++) acc[n] += as[n][k] * wl + xs[n][k] * wr;
    }
    float bias = b1[t];
#pragma unroll
    for (int n = 0; n < 8; n++) {
        int node = nb + n;
        if (node < N_NODES) {
            float v = acc[n] + bias;
            h[(size_t)node * HIDDEN + t] = v > 0.f ? v : 0.f;
        }
    }
}

// ---------------- GEMM2: out = agg2m @ W2_l^T + b2 + h @ W2_r^T ----------------
// 8 nodes per block, 256 threads = 4 groups x 64 channels; each group does 2 nodes
__global__ void gemm2_k(const float* __restrict__ h, const float* __restrict__ agg,
                        const int* __restrict__ cnt,
                        const float* __restrict__ W2lT, const float* __restrict__ W2rT,
                        const float* __restrict__ b2, float* __restrict__ out) {
    __shared__ float hs[8][HIDDEN];
    __shared__ float as[8][HIDDEN];
    int nb = blockIdx.x * 8;
    int t = threadIdx.x;
    for (int i = t; i < 8 * HIDDEN; i += 256) {
        int n = i / HIDDEN, k = i % HIDDEN;
        int node = nb + n;
        float hv = 0.f, av = 0.f;
        if (node < N_NODES) {
            hv = h[(size_t)node * HIDDEN + k];
            int c = cnt[node]; if (c < 1) c = 1;
            av = agg[(size_t)node * HIDDEN + k] / (float)c;
        }
        hs[n][k] = hv; as[n][k] = av;
    }
    __syncthreads();
    int j = t & 63, g = t >> 6;
    float acc[2] = {0.f, 0.f};
    for (int k = 0; k < HIDDEN; k++) {
        float wl = W2lT[k * OUT_F + j];
        float wr = W2rT[k * OUT_F + j];
#pragma unroll
        for (int n = 0; n < 2; n++) {
            int nn = g * 2 + n;
            acc[n] += as[nn][k] * wl + hs[nn][k] * wr;
        }
    }
    float bias = b2[j];
#pragma unroll
    for (int n = 0; n < 2; n++) {
        int node = nb + g * 2 + n;
        if (node < N_NODES) out[(size_t)node * OUT_F + j] = acc[n] + bias;
    }
}

extern "C" void kernel_launch(void* const* d_in, const int* in_sizes, int n_in,
                              void* d_out, int out_size, void* d_ws, size_t ws_size,
                              hipStream_t stream) {
    const float* x    = (const float*)d_in[0];
    const int*   eidx = (const int*)d_in[1];
    const float* W1l  = (const float*)d_in[2];
    const float* W1r  = (const float*)d_in[3];
    const float* b1   = (const float*)d_in[4];
    const float* W2l  = (const float*)d_in[5];
    const float* W2r  = (const float*)d_in[6];
    const float* b2   = (const float*)d_in[7];
    float* out = (float*)d_out;

    const int* src = eidx;             // edge_index[0]
    const int* dst = eidx + N_EDGES;   // edge_index[1]

    // workspace layout (floats)
    float* ws   = (float*)d_ws;
    float* bufA = ws;                          // 12.8M floats: agg1 (first 6.4M), later agg2 (all)
    float* hbuf = ws + (size_t)N_NODES * HIDDEN;            // 12.8M floats
    float* wts  = hbuf + (size_t)N_NODES * HIDDEN;          // transposed weights
    float* W1lT = wts;                  // 128*256
    float* W1rT = wts + 32768;          // 128*256
    float* W2lT = wts + 65536;          // 256*64
    float* W2rT = wts + 81920;          // 256*64
    int*   cnt  = (int*)(wts + 98304);  // 50000 ints

    float* agg1 = bufA;
    float* agg2 = bufA;

    // 0) zero cnt + agg1
    hipMemsetAsync(cnt, 0, (size_t)N_NODES * sizeof(int), stream);
    hipMemsetAsync(agg1, 0, (size_t)N_NODES * IN_FEAT * sizeof(float), stream);

    // 1) transposes (small)
    transpose_k<<<(HIDDEN * IN_FEAT + 255) / 256, 256, 0, stream>>>(W1l, W1lT, HIDDEN, IN_FEAT);
    transpose_k<<<(HIDDEN * IN_FEAT + 255) / 256, 256, 0, stream>>>(W1r, W1rT, HIDDEN, IN_FEAT);
    transpose_k<<<(OUT_F * HIDDEN + 255) / 256, 256, 0, stream>>>(W2l, W2lT, OUT_F, HIDDEN);
    transpose_k<<<(OUT_F * HIDDEN + 255) / 256, 256, 0, stream>>>(W2r, W2rT, OUT_F, HIDDEN);

    // 2) degree count
    count_edges_k<<<(N_EDGES + 255) / 256, 256, 0, stream>>>(dst, cnt);

    // 3) scatter layer 1
    scatter1_k<<<N_EDGES, IN_FEAT, 0, stream>>>(x, src, dst, agg1);

    // 4) GEMM1 -> h
    gemm1_k<<<(N_NODES + 7) / 8, 256, 0, stream>>>(x, agg1, cnt, W1lT, W1rT, b1, hbuf);

    // 5) zero agg2 (reuses bufA; agg1 no longer needed)
    hipMemsetAsync(agg2, 0, (size_t)N_NODES * HIDDEN * sizeof(float), stream);

    // 6) scatter layer 2
    scatter2_k<<<N_EDGES, HIDDEN, 0, stream>>>(hbuf, src, dst, agg2);

    // 7) GEMM2 -> out
    gemm2_k<<<(N_NODES + 7) / 8, 256, 0, stream>>>(hbuf, agg2, cnt, W2lT, W2rT, b2, out);
}

// Round 2
// 594.874 us; speedup vs baseline: 2.2698x; 2.2698x over previous
//
#include <hip/hip_runtime.h>
#include <hip/hip_bf16.h>

#define N_NODES 50000
#define N_EDGES 800000
#define IN_FEAT 128
#define HIDDEN  256
#define OUT_F   64

// ---------------- degree count ----------------
__global__ void count_edges_k(const int* __restrict__ dst, int* __restrict__ cnt) {
    int e = blockIdx.x * blockDim.x + threadIdx.x;
    if (e < N_EDGES) atomicAdd(&cnt[dst[e]], 1);
}

// ---------------- single-block exclusive scan over cnt -> rowptr ----------------
__global__ __launch_bounds__(1024) void scan_k(const int* __restrict__ cnt,
                                               int* __restrict__ rowptr) {
    __shared__ int part[1024];
    int t = threadIdx.x;
    const int CH = (N_NODES + 1023) / 1024;   // 49
    int begin = t * CH;
    int end = begin + CH; if (end > N_NODES) end = N_NODES;
    int s = 0;
    for (int i = begin; i < end && i < N_NODES; i++) s += cnt[i];
    part[t] = s;
    __syncthreads();
    // inclusive scan (Hillis-Steele)
    for (int off = 1; off < 1024; off <<= 1) {
        int add = (t >= off) ? part[t - off] : 0;
        __syncthreads();
        part[t] += add;
        __syncthreads();
    }
    int run = (t == 0) ? 0 : part[t - 1];
    for (int i = begin; i < end && i < N_NODES; i++) { rowptr[i] = run; run += cnt[i]; }
    if (t == 1023) rowptr[N_NODES] = part[1023];
}

// ---------------- CSR fill: eids[rowptr[dst]+k] = src ----------------
__global__ void fill_k(const int* __restrict__ src, const int* __restrict__ dst,
                       const int* __restrict__ rowptr, int* __restrict__ fill,
                       int* __restrict__ eids) {
    int e = blockIdx.x * blockDim.x + threadIdx.x;
    if (e < N_EDGES) {
        int d = dst[e];
        int pos = rowptr[d] + atomicAdd(&fill[d], 1);
        eids[pos] = src[e];
    }
}

// ---------------- W[R][C] -> WT[C][R] ----------------
__global__ void transpose_k(const float* __restrict__ W, float* __restrict__ WT,
                            int R, int C) {
    int i = blockIdx.x * blockDim.x + threadIdx.x;
    if (i < R * C) {
        int r = i / C, c = i % C;
        WT[c * R + r] = W[i];
    }
}

// ---------------- gather-mean layer 1: agg1[n] = mean_{e->n} x[src], 128 f ----------------
// one wave per node, float2 per lane
__global__ void gather1_k(const float* __restrict__ x, const int* __restrict__ eids,
                          const int* __restrict__ rowptr, float* __restrict__ agg) {
    int w = threadIdx.x >> 6, lane = threadIdx.x & 63;
    int node = blockIdx.x * 4 + w;
    if (node >= N_NODES) return;
    int b = rowptr[node], e = rowptr[node + 1];
    float a0 = 0.f, a1 = 0.f;
    for (int i = b; i < e; i++) {
        int s = eids[i];
        float2 v = ((const float2*)(x + (size_t)s * IN_FEAT))[lane];
        a0 += v.x; a1 += v.y;
    }
    int deg = e - b; if (deg < 1) deg = 1;
    float inv = 1.0f / (float)deg;
    float2 r; r.x = a0 * inv; r.y = a1 * inv;
    ((float2*)(agg + (size_t)node * IN_FEAT))[lane] = r;
}

// ---------------- GEMM1: h = relu(agg1 @ W1_l^T + b1 + x @ W1_r^T) ----------------
// 8 nodes per block, 256 threads (thread = output channel)
__global__ void gemm1_k(const float* __restrict__ x, const float* __restrict__ agg,
                        const float* __restrict__ W1lT, const float* __restrict__ W1rT,
                        const float* __restrict__ b1, float* __restrict__ h) {
    __shared__ float xs[8][IN_FEAT];
    __shared__ float as[8][IN_FEAT];
    int nb = blockIdx.x * 8;
    int t = threadIdx.x;
    {   // 256 float4 loads cover 8 rows x 32 float4
        int n = t >> 5, k4 = t & 31;
        int node = nb + n;
        float4 xv = make_float4(0.f, 0.f, 0.f, 0.f), av = xv;
        if (node < N_NODES) {
            xv = ((const float4*)(x + (size_t)node * IN_FEAT))[k4];
            av = ((const float4*)(agg + (size_t)node * IN_FEAT))[k4];
        }
        ((float4*)xs[n])[k4] = xv;
        ((float4*)as[n])[k4] = av;
    }
    __syncthreads();
    float acc[8];
#pragma unroll
    for (int n = 0; n < 8; n++) acc[n] = 0.f;
#pragma unroll 4
    for (int k = 0; k < IN_FEAT; k++) {
        float wl = W1lT[k * HIDDEN + t];
        float wr = W1rT[k * HIDDEN + t];
#pragma unroll
        for (int n = 0; n < 8; n++) acc[n] += as[n][k] * wl + xs[n][k] * wr;
    }
    float bias = b1[t];
#pragma unroll
    for (int n = 0; n < 8; n++) {
        int node = nb + n;
        if (node < N_NODES) {
            float v = acc[n] + bias;
            h[(size_t)node * HIDDEN + t] = v > 0.f ? v : 0.f;
        }
    }
}

// ---------------- GEMM2 fused: y = h @ W2_l^T ; out = h @ W2_r^T + b2 ----------------
// 8 nodes per block, 256 threads = 4 waves x 64 channels; each wave does 2 nodes
__global__ void gemm2_k(const float* __restrict__ h,
                        const float* __restrict__ W2lT, const float* __restrict__ W2rT,
                        const float* __restrict__ b2,
                        float* __restrict__ y, float* __restrict__ out) {
    __shared__ float hs[8][HIDDEN];
    int nb = blockIdx.x * 8;
    int t = threadIdx.x;
    for (int i = t; i < 512; i += 256) {     // 512 float4 cover 8 rows x 64 float4
        int n = i >> 6, k4 = i & 63;
        int node = nb + n;
        float4 hv = make_float4(0.f, 0.f, 0.f, 0.f);
        if (node < N_NODES) hv = ((const float4*)(h + (size_t)node * HIDDEN))[k4];
        ((float4*)hs[n])[k4] = hv;
    }
    __syncthreads();
    int j = t & 63, g = t >> 6;
    float accl[2] = {0.f, 0.f}, accr[2] = {0.f, 0.f};
#pragma unroll 4
    for (int k = 0; k < HIDDEN; k++) {
        float wl = W2lT[k * OUT_F + j];
        float wr = W2rT[k * OUT_F + j];
#pragma unroll
        for (int n = 0; n < 2; n++) {
            float hv = hs[g * 2 + n][k];
            accl[n] += hv * wl;
            accr[n] += hv * wr;
        }
    }
    float bias = b2[j];
#pragma unroll
    for (int n = 0; n < 2; n++) {
        int node = nb + g * 2 + n;
        if (node < N_NODES) {
            y[(size_t)node * OUT_F + j] = accl[n];
            out[(size_t)node * OUT_F + j] = accr[n] + bias;
        }
    }
}

// ---------------- gather-mean layer 2: out[n] += mean_{e->n} y[src], 64 f ----------------
__global__ void gather2_k(const float* __restrict__ y, const int* __restrict__ eids,
                          const int* __restrict__ rowptr, float* __restrict__ out) {
    int w = threadIdx.x >> 6, lane = threadIdx.x & 63;
    int node = blockIdx.x * 4 + w;
    if (node >= N_NODES) return;
    int b = rowptr[node], e = rowptr[node + 1];
    float a = 0.f;
    for (int i = b; i < e; i++) {
        int s = eids[i];
        a += y[(size_t)s * OUT_F + lane];
    }
    int deg = e - b; if (deg < 1) deg = 1;
    out[(size_t)node * OUT_F + lane] += a / (float)deg;
}

extern "C" void kernel_launch(void* const* d_in, const int* in_sizes, int n_in,
                              void* d_out, int out_size, void* d_ws, size_t ws_size,
                              hipStream_t stream) {
    const float* x    = (const float*)d_in[0];
    const int*   eidx = (const int*)d_in[1];
    const float* W1l  = (const float*)d_in[2];
    const float* W1r  = (const float*)d_in[3];
    const float* b1   = (const float*)d_in[4];
    const float* W2l  = (const float*)d_in[5];
    const float* W2r  = (const float*)d_in[6];
    const float* b2   = (const float*)d_in[7];
    float* out = (float*)d_out;

    const int* src = eidx;             // edge_index[0]
    const int* dst = eidx + N_EDGES;   // edge_index[1]

    // workspace layout
    float* ws   = (float*)d_ws;
    float* hbuf = ws;                                        // 12.8M floats
    float* agg1 = hbuf + (size_t)N_NODES * HIDDEN;           // 6.4M floats
    float* ybuf = agg1 + (size_t)N_NODES * IN_FEAT;          // 3.2M floats
    float* wts  = ybuf + (size_t)N_NODES * OUT_F;
    float* W1lT = wts;                  // 128*256
    float* W1rT = wts + 32768;          // 128*256
    float* W2lT = wts + 65536;          // 256*64
    float* W2rT = wts + 81920;          // 256*64
    int*   cnt    = (int*)(wts + 98304);          // 50000
    int*   fill   = cnt + N_NODES;                // 50000
    int*   rowptr = fill + N_NODES;               // 50001
    int*   eids   = rowptr + N_NODES + 1;         // 800000

    // 0) zero cnt + fill
    hipMemsetAsync(cnt, 0, (size_t)N_NODES * sizeof(int), stream);
    hipMemsetAsync(fill, 0, (size_t)N_NODES * sizeof(int), stream);

    // 1) weight transposes (small)
    transpose_k<<<(HIDDEN * IN_FEAT + 255) / 256, 256, 0, stream>>>(W1l, W1lT, HIDDEN, IN_FEAT);
    transpose_k<<<(HIDDEN * IN_FEAT + 255) / 256, 256, 0, stream>>>(W1r, W1rT, HIDDEN, IN_FEAT);
    transpose_k<<<(OUT_F * HIDDEN + 255) / 256, 256, 0, stream>>>(W2l, W2lT, OUT_F, HIDDEN);
    transpose_k<<<(OUT_F * HIDDEN + 255) / 256, 256, 0, stream>>>(W2r, W2rT, OUT_F, HIDDEN);

    // 2) CSR build
    count_edges_k<<<(N_EDGES + 255) / 256, 256, 0, stream>>>(dst, cnt);
    scan_k<<<1, 1024, 0, stream>>>(cnt, rowptr);
    fill_k<<<(N_EDGES + 255) / 256, 256, 0, stream>>>(src, dst, rowptr, fill, eids);

    // 3) layer-1 aggregation (gather-mean)
    gather1_k<<<(N_NODES + 3) / 4, 256, 0, stream>>>(x, eids, rowptr, agg1);

    // 4) GEMM1 -> h
    gemm1_k<<<(N_NODES + 7) / 8, 256, 0, stream>>>(x, agg1, W1lT, W1rT, b1, hbuf);

    // 5) GEMM2 -> y, out(partial)
    gemm2_k<<<(N_NODES + 7) / 8, 256, 0, stream>>>(hbuf, W2lT, W2rT, b2, ybuf, out);

    // 6) layer-2 aggregation (gather-mean, post-transform)
    gather2_k<<<(N_NODES + 3) / 4, 256, 0, stream>>>(ybuf, eids, rowptr, out);
}

// Round 3
// 412.436 us; speedup vs baseline: 3.2738x; 1.4423x over previous
//
#include <hip/hip_runtime.h>
#include <hip/hip_bf16.h>

#define N_NODES 50000
#define N_EDGES 800000
#define IN_FEAT 128
#define HIDDEN  256
#define OUT_F   64
#define M_PAD   50048   // 782 * 64

typedef __attribute__((ext_vector_type(8))) short short8;
typedef __attribute__((ext_vector_type(4))) float f32x4;

static __device__ __forceinline__ unsigned short f2bf(float f) {
    unsigned u = __float_as_uint(f);
    unsigned r = (u + 0x7fffu + ((u >> 16) & 1u)) >> 16;   // RNE
    return (unsigned short)r;
}

// ---------------- degree count ----------------
__global__ void count_edges_k(const int* __restrict__ dst, int* __restrict__ cnt) {
    int e = blockIdx.x * blockDim.x + threadIdx.x;
    if (e < N_EDGES) atomicAdd(&cnt[dst[e]], 1);
}

// ---------------- single-block exclusive scan over cnt -> rowptr ----------------
__global__ __launch_bounds__(1024) void scan_k(const int* __restrict__ cnt,
                                               int* __restrict__ rowptr) {
    __shared__ int part[1024];
    int t = threadIdx.x;
    const int CH = (N_NODES + 1023) / 1024;   // 49
    int begin = t * CH;
    int end = begin + CH; if (end > N_NODES) end = N_NODES;
    int s = 0;
    for (int i = begin; i < end && i < N_NODES; i++) s += cnt[i];
    part[t] = s;
    __syncthreads();
    for (int off = 1; off < 1024; off <<= 1) {
        int add = (t >= off) ? part[t - off] : 0;
        __syncthreads();
        part[t] += add;
        __syncthreads();
    }
    int run = (t == 0) ? 0 : part[t - 1];
    for (int i = begin; i < end && i < N_NODES; i++) { rowptr[i] = run; run += cnt[i]; }
    if (t == 1023) rowptr[N_NODES] = part[1023];
}

// ---------------- CSR fill ----------------
__global__ void fill_k(const int* __restrict__ src, const int* __restrict__ dst,
                       const int* __restrict__ rowptr, int* __restrict__ fill,
                       int* __restrict__ eids) {
    int e = blockIdx.x * blockDim.x + threadIdx.x;
    if (e < N_EDGES) {
        int d = dst[e];
        int pos = rowptr[d] + atomicAdd(&fill[d], 1);
        eids[pos] = src[e];
    }
}

// ---------------- convert x -> bf16 into A1[:,128:256] ----------------
__global__ void convert_x_k(const float* __restrict__ x, unsigned int* __restrict__ A1u) {
    int i = blockIdx.x * blockDim.x + threadIdx.x;   // pair index
    if (i >= N_NODES * 64) return;
    int n = i >> 6, p = i & 63;
    float2 v = ((const float2*)(x + (size_t)n * IN_FEAT))[p];
    A1u[(size_t)n * 128 + 64 + p] = (unsigned)f2bf(v.x) | ((unsigned)f2bf(v.y) << 16);
}

// ---------------- W1cat[n][k] bf16: k<128 -> W1l, k>=128 -> W1r ----------------
__global__ void convert_w1_k(const float* __restrict__ W1l, const float* __restrict__ W1r,
                             unsigned short* __restrict__ Wc) {
    int i = blockIdx.x * blockDim.x + threadIdx.x;   // 65536
    int n = i >> 8, k = i & 255;
    float v = (k < 128) ? W1l[n * 128 + k] : W1r[n * 128 + (k - 128)];
    Wc[i] = f2bf(v);
}

// ---------------- W2cat[n][k] bf16: n<64 -> W2l (y), n>=64 -> W2r (out) ----------------
__global__ void convert_w2_k(const float* __restrict__ W2l, const float* __restrict__ W2r,
                             unsigned short* __restrict__ Wc) {
    int i = blockIdx.x * blockDim.x + threadIdx.x;   // 32768
    int n = i >> 8, k = i & 255;
    float v = (n < 64) ? W2l[n * 256 + k] : W2r[(n - 64) * 256 + k];
    Wc[i] = f2bf(v);
}

// ---------------- gather-mean layer 1 (bf16): A1[:,0:128] = mean x[src] ----------------
// one wave per node; lane = u32 pair of channels
__global__ void gather1_k(const unsigned int* __restrict__ Au, const int* __restrict__ eids,
                          const int* __restrict__ rowptr, unsigned int* __restrict__ Aw) {
    int w = threadIdx.x >> 6, lane = threadIdx.x & 63;
    int node = blockIdx.x * 4 + w;
    if (node >= N_NODES) return;
    int b = rowptr[node], e = rowptr[node + 1];
    float a0 = 0.f, a1 = 0.f;
    for (int i = b; i < e; i++) {
        int s = eids[i];
        unsigned u = Au[(size_t)s * 128 + 64 + lane];
        a0 += __uint_as_float(u << 16);
        a1 += __uint_as_float(u & 0xffff0000u);
    }
    int deg = e - b; if (deg < 1) deg = 1;
    float inv = 1.f / (float)deg;
    Aw[(size_t)node * 128 + lane] =
        (unsigned)f2bf(a0 * inv) | ((unsigned)f2bf(a1 * inv) << 16);
}

// ---------------- MFMA GEMM1: h = relu(A1 @ W1cat^T + b1), M=50k N=256 K=256 ----------------
// 4 waves/block, wave = 16 rows x 256 cols; A-frags in regs, B-frags from L2
__global__ __launch_bounds__(256) void mfma_gemm1_k(
        const unsigned short* __restrict__ A, const unsigned short* __restrict__ W,
        const float* __restrict__ b1, unsigned short* __restrict__ h) {
    int wv = threadIdx.x >> 6, lane = threadIdx.x & 63;
    int row = lane & 15, kg = lane >> 4;          // frag row, k-group
    int m0 = blockIdx.x * 64 + wv * 16;
    const short8* arow = (const short8*)(A + (size_t)(m0 + row) * 256 + kg * 8);
    short8 af[8];
#pragma unroll
    for (int ks = 0; ks < 8; ks++) af[ks] = arow[ks * 4];
    f32x4 acc[16];
#pragma unroll
    for (int nt = 0; nt < 16; nt++) acc[nt] = (f32x4)(0.f);
#pragma unroll
    for (int ks = 0; ks < 8; ks++) {
#pragma unroll
        for (int nt = 0; nt < 16; nt++) {
            short8 bf = *(const short8*)(W + ((nt * 16 + row) << 8) + ks * 32 + kg * 8);
            acc[nt] = __builtin_amdgcn_mfma_f32_16x16x32_bf16(af[ks], bf, acc[nt], 0, 0, 0);
        }
    }
    int r0 = m0 + (lane >> 4) * 4;
    int col = lane & 15;
#pragma unroll
    for (int nt = 0; nt < 16; nt++) {
        int c = nt * 16 + col;
        float bias = b1[c];
#pragma unroll
        for (int i = 0; i < 4; i++) {
            int rr = r0 + i;
            if (rr < N_NODES) {
                float v = acc[nt][i] + bias;
                v = v > 0.f ? v : 0.f;
                h[(size_t)rr * 256 + c] = f2bf(v);
            }
        }
    }
}

// ---------------- MFMA GEMM2: [y | out_r] = h @ W2cat^T, M=50k N=128 K=256 ----------------
__global__ __launch_bounds__(256) void mfma_gemm2_k(
        const unsigned short* __restrict__ A, const unsigned short* __restrict__ W,
        const float* __restrict__ b2, unsigned short* __restrict__ y,
        float* __restrict__ out) {
    int wv = threadIdx.x >> 6, lane = threadIdx.x & 63;
    int row = lane & 15, kg = lane >> 4;
    int m0 = blockIdx.x * 64 + wv * 16;
    const short8* arow = (const short8*)(A + (size_t)(m0 + row) * 256 + kg * 8);
    short8 af[8];
#pragma unroll
    for (int ks = 0; ks < 8; ks++) af[ks] = arow[ks * 4];
    f32x4 acc[8];
#pragma unroll
    for (int nt = 0; nt < 8; nt++) acc[nt] = (f32x4)(0.f);
#pragma unroll
    for (int ks = 0; ks < 8; ks++) {
#pragma unroll
        for (int nt = 0; nt < 8; nt++) {
            short8 bf = *(const short8*)(W + ((nt * 16 + row) << 8) + ks * 32 + kg * 8);
            acc[nt] = __builtin_amdgcn_mfma_f32_16x16x32_bf16(af[ks], bf, acc[nt], 0, 0, 0);
        }
    }
    int r0 = m0 + (lane >> 4) * 4;
    int col = lane & 15;
#pragma unroll
    for (int nt = 0; nt < 8; nt++) {
        int c = nt * 16 + col;   // 0..127
#pragma unroll
        for (int i = 0; i < 4; i++) {
            int rr = r0 + i;
            if (rr < N_NODES) {
                if (nt < 4) {
                    y[(size_t)rr * OUT_F + c] = f2bf(acc[nt][i]);
                } else {
                    out[(size_t)rr * OUT_F + (c - 64)] = acc[nt][i] + b2[c - 64];
                }
            }
        }
    }
}

// ---------------- gather-mean layer 2: out[n] += mean y[src], 64 bf16 feats ----------------
// one wave per node; 2 edges in parallel (lane halves), u32 pair of channels
__global__ void gather2_k(const unsigned short* __restrict__ y, const int* __restrict__ eids,
                          const int* __restrict__ rowptr, float* __restrict__ out) {
    int w = threadIdx.x >> 6, lane = threadIdx.x & 63;
    int node = blockIdx.x * 4 + w;
    if (node >= N_NODES) return;
    int b = rowptr[node], e = rowptr[node + 1];
    int half = lane >> 5, c2 = lane & 31;
    float a0 = 0.f, a1 = 0.f;
    for (int i = b + half; i < e; i += 2) {
        int s = eids[i];
        unsigned u = ((const unsigned*)(y + (size_t)s * OUT_F))[c2];
        a0 += __uint_as_float(u << 16);
        a1 += __uint_as_float(u & 0xffff0000u);
    }
    a0 += __shfl_xor(a0, 32);
    a1 += __shfl_xor(a1, 32);
    if (half == 0) {
        int deg = e - b; if (deg < 1) deg = 1;
        float inv = 1.f / (float)deg;
        float2* p = (float2*)(out + (size_t)node * OUT_F + 2 * c2);
        float2 cur = *p;
        cur.x += a0 * inv; cur.y += a1 * inv;
        *p = cur;
    }
}

extern "C" void kernel_launch(void* const* d_in, const int* in_sizes, int n_in,
                              void* d_out, int out_size, void* d_ws, size_t ws_size,
                              hipStream_t stream) {
    const float* x    = (const float*)d_in[0];
    const int*   eidx = (const int*)d_in[1];
    const float* W1l  = (const float*)d_in[2];
    const float* W1r  = (const float*)d_in[3];
    const float* b1   = (const float*)d_in[4];
    const float* W2l  = (const float*)d_in[5];
    const float* W2r  = (const float*)d_in[6];
    const float* b2   = (const float*)d_in[7];
    float* out = (float*)d_out;

    const int* src = eidx;             // edge_index[0]
    const int* dst = eidx + N_EDGES;   // edge_index[1]

    // workspace layout (ushort units)
    unsigned short* A1   = (unsigned short*)d_ws;              // [M_PAD][256] bf16
    unsigned short* hbuf = A1 + (size_t)M_PAD * 256;           // [M_PAD][256] bf16
    unsigned short* ybuf = hbuf + (size_t)M_PAD * 256;         // [M_PAD][64]  bf16
    unsigned short* W1c  = ybuf + (size_t)M_PAD * OUT_F;       // 256*256
    unsigned short* W2c  = W1c + 256 * 256;                    // 128*256
    int* cnt    = (int*)(W2c + 128 * 256);
    int* fill   = cnt + N_NODES;
    int* rowptr = fill + N_NODES;
    int* eids   = rowptr + N_NODES + 1;

    hipMemsetAsync(cnt, 0, (size_t)N_NODES * sizeof(int), stream);
    hipMemsetAsync(fill, 0, (size_t)N_NODES * sizeof(int), stream);

    // conversions
    convert_x_k<<<(N_NODES * 64 + 255) / 256, 256, 0, stream>>>(x, (unsigned int*)A1);
    convert_w1_k<<<256, 256, 0, stream>>>(W1l, W1r, W1c);
    convert_w2_k<<<128, 256, 0, stream>>>(W2l, W2r, W2c);

    // CSR build
    count_edges_k<<<(N_EDGES + 255) / 256, 256, 0, stream>>>(dst, cnt);
    scan_k<<<1, 1024, 0, stream>>>(cnt, rowptr);
    fill_k<<<(N_EDGES + 255) / 256, 256, 0, stream>>>(src, dst, rowptr, fill, eids);

    // layer-1 aggregation (gather-mean, bf16)
    gather1_k<<<(N_NODES + 3) / 4, 256, 0, stream>>>((const unsigned int*)A1, eids, rowptr,
                                                     (unsigned int*)A1);

    // GEMM1 -> h (bf16)
    mfma_gemm1_k<<<M_PAD / 64, 256, 0, stream>>>(A1, W1c, b1, hbuf);

    // GEMM2 -> y (bf16), out_r + b2 (fp32)
    mfma_gemm2_k<<<M_PAD / 64, 256, 0, stream>>>(hbuf, W2c, b2, ybuf, out);

    // layer-2 aggregation
    gather2_k<<<(N_NODES + 3) / 4, 256, 0, stream>>>(ybuf, eids, rowptr, out);
}

// Round 4
// 337.464 us; speedup vs baseline: 4.0011x; 1.2222x over previous
//
#include <hip/hip_runtime.h>
#include <hip/hip_bf16.h>

#define N_NODES 50000
#define N_EDGES 800000
#define IN_FEAT 128
#define HIDDEN  256
#define OUT_F   64
#define M_PAD   50048   // 782 * 64

typedef __attribute__((ext_vector_type(8))) short short8;
typedef __attribute__((ext_vector_type(4))) float f32x4;

static __device__ __forceinline__ unsigned short f2bf(float f) {
    unsigned u = __float_as_uint(f);
    unsigned r = (u + 0x7fffu + ((u >> 16) & 1u)) >> 16;   // RNE
    return (unsigned short)r;
}

// ---------------- degree count ----------------
__global__ void count_edges_k(const int* __restrict__ dst, int* __restrict__ cnt) {
    int e = blockIdx.x * blockDim.x + threadIdx.x;
    if (e < N_EDGES) atomicAdd(&cnt[dst[e]], 1);
}

// ---------------- single-block exclusive scan over cnt -> rowptr ----------------
__global__ __launch_bounds__(1024) void scan_k(const int* __restrict__ cnt,
                                               int* __restrict__ rowptr) {
    __shared__ int part[1024];
    int t = threadIdx.x;
    const int CH = (N_NODES + 1023) / 1024;   // 49
    int begin = t * CH;
    int end = begin + CH; if (end > N_NODES) end = N_NODES;
    int s = 0;
    for (int i = begin; i < end && i < N_NODES; i++) s += cnt[i];
    part[t] = s;
    __syncthreads();
    for (int off = 1; off < 1024; off <<= 1) {
        int add = (t >= off) ? part[t - off] : 0;
        __syncthreads();
        part[t] += add;
        __syncthreads();
    }
    int run = (t == 0) ? 0 : part[t - 1];
    for (int i = begin; i < end && i < N_NODES; i++) { rowptr[i] = run; run += cnt[i]; }
    if (t == 1023) rowptr[N_NODES] = part[1023];
}

// ---------------- CSR fill ----------------
__global__ void fill_k(const int* __restrict__ src, const int* __restrict__ dst,
                       const int* __restrict__ rowptr, int* __restrict__ fill,
                       int* __restrict__ eids) {
    int e = blockIdx.x * blockDim.x + threadIdx.x;
    if (e < N_EDGES) {
        int d = dst[e];
        int pos = rowptr[d] + atomicAdd(&fill[d], 1);
        eids[pos] = src[e];
    }
}

// ---------------- convert x -> bf16 into A1[:,128:256] ----------------
__global__ void convert_x_k(const float* __restrict__ x, unsigned int* __restrict__ A1u) {
    int i = blockIdx.x * blockDim.x + threadIdx.x;   // pair index
    if (i >= N_NODES * 64) return;
    int n = i >> 6, p = i & 63;
    float2 v = ((const float2*)(x + (size_t)n * IN_FEAT))[p];
    A1u[(size_t)n * 128 + 64 + p] = (unsigned)f2bf(v.x) | ((unsigned)f2bf(v.y) << 16);
}

// ---------------- W1 -> MFMA fragment layout Wf1[ks][nt][lane][8] (bf16) ----------------
// fragment element: n = nt*16 + (lane&15), k = ks*32 + (lane>>4)*8 + j
// k<128 -> W1l (agg part), k>=128 -> W1r (x part)
__global__ void convert_w1_k(const float* __restrict__ W1l, const float* __restrict__ W1r,
                             unsigned int* __restrict__ Wf) {
    int i = blockIdx.x * blockDim.x + threadIdx.x;   // 32768 u32
    if (i >= 32768) return;
    int s = i * 2;
    int j = s & 7, lane = (s >> 3) & 63, nt = (s >> 9) & 15, ks = s >> 13;
    int n = nt * 16 + (lane & 15);
    int k = ks * 32 + ((lane >> 4) << 3) + j;
    float v0, v1;
    if (k < 128) { v0 = W1l[n * 128 + k];       v1 = W1l[n * 128 + k + 1]; }
    else         { v0 = W1r[n * 128 + k - 128]; v1 = W1r[n * 128 + k - 127]; }
    Wf[i] = (unsigned)f2bf(v0) | ((unsigned)f2bf(v1) << 16);
}

// ---------------- W2 -> fragment layout Wf2[ks][nt][lane][8]; n<64 -> W2l, else W2r ----------------
__global__ void convert_w2_k(const float* __restrict__ W2l, const float* __restrict__ W2r,
                             unsigned int* __restrict__ Wf) {
    int i = blockIdx.x * blockDim.x + threadIdx.x;   // 16384 u32
    if (i >= 16384) return;
    int s = i * 2;
    int j = s & 7, lane = (s >> 3) & 63, nt = (s >> 9) & 7, ks = s >> 12;
    int n = nt * 16 + (lane & 15);
    int k = ks * 32 + ((lane >> 4) << 3) + j;
    float v0, v1;
    if (n < 64) { v0 = W2l[n * 256 + k];        v1 = W2l[n * 256 + k + 1]; }
    else        { v0 = W2r[(n - 64) * 256 + k]; v1 = W2r[(n - 64) * 256 + k + 1]; }
    Wf[i] = (unsigned)f2bf(v0) | ((unsigned)f2bf(v1) << 16);
}

// ---------------- gather-mean layer 1 (bf16): A1[:,0:128] = mean x[src] ----------------
__global__ void gather1_k(const unsigned int* __restrict__ Au, const int* __restrict__ eids,
                          const int* __restrict__ rowptr, unsigned int* __restrict__ Aw) {
    int w = threadIdx.x >> 6, lane = threadIdx.x & 63;
    int node = blockIdx.x * 4 + w;
    if (node >= N_NODES) return;
    int b = rowptr[node], e = rowptr[node + 1];
    float a0 = 0.f, a1 = 0.f;
    for (int i = b; i < e; i++) {
        int s = eids[i];
        unsigned u = Au[(size_t)s * 128 + 64 + lane];
        a0 += __uint_as_float(u << 16);
        a1 += __uint_as_float(u & 0xffff0000u);
    }
    int deg = e - b; if (deg < 1) deg = 1;
    float inv = 1.f / (float)deg;
    Aw[(size_t)node * 128 + lane] =
        (unsigned)f2bf(a0 * inv) | ((unsigned)f2bf(a1 * inv) << 16);
}

// ---------------- MFMA GEMM1: h = relu(A1 @ W1cat^T + b1), M=M_PAD N=256 K=256 ----------------
// 4 waves/block; wave = 32 rows x 128 cols; block = 64 rows x 256 cols.
// B-fragments from pre-swizzled Wf1 (coalesced); A-fragments hoisted to registers.
__global__ __launch_bounds__(256) void mfma_gemm1_k(
        const unsigned short* __restrict__ A, const unsigned short* __restrict__ Wf,
        const float* __restrict__ b1, unsigned short* __restrict__ h) {
    int wv = threadIdx.x >> 6, lane = threadIdx.x & 63;
    int rowh = wv >> 1, colh = wv & 1;
    int m0 = blockIdx.x * 64 + rowh * 32;
    int row = lane & 15, kg = lane >> 4;
    const short8* Wf8 = (const short8*)Wf;

    short8 af[2][8];
#pragma unroll
    for (int mt = 0; mt < 2; mt++) {
        const short8* ar = (const short8*)(A + (size_t)(m0 + mt * 16 + row) * 256 + kg * 8);
#pragma unroll
        for (int ks = 0; ks < 8; ks++) af[mt][ks] = ar[ks * 4];
    }
    f32x4 acc[2][8];
#pragma unroll
    for (int mt = 0; mt < 2; mt++)
#pragma unroll
        for (int nt = 0; nt < 8; nt++) acc[mt][nt] = (f32x4)(0.f);

#pragma unroll
    for (int ks = 0; ks < 8; ks++) {
        short8 bf[8];
#pragma unroll
        for (int nt = 0; nt < 8; nt++)
            bf[nt] = Wf8[(ks * 16 + colh * 8 + nt) * 64 + lane];
#pragma unroll
        for (int nt = 0; nt < 8; nt++) {
#pragma unroll
            for (int mt = 0; mt < 2; mt++)
                acc[mt][nt] = __builtin_amdgcn_mfma_f32_16x16x32_bf16(af[mt][ks], bf[nt],
                                                                      acc[mt][nt], 0, 0, 0);
        }
    }

#pragma unroll
    for (int mt = 0; mt < 2; mt++) {
        int r0 = m0 + mt * 16 + kg * 4;
#pragma unroll
        for (int nt = 0; nt < 8; nt++) {
            int c = colh * 128 + nt * 16 + row;
            float bias = b1[c];
#pragma unroll
            for (int i = 0; i < 4; i++) {
                float v = acc[mt][nt][i] + bias;
                v = v > 0.f ? v : 0.f;
                h[(size_t)(r0 + i) * 256 + c] = f2bf(v);
            }
        }
    }
}

// ---------------- MFMA GEMM2: [y | out_r] = h @ W2cat^T, M=M_PAD N=128 K=256 ----------------
// 4 waves/block; wave = 32 rows x 128 cols (full N); block = 128 rows.
__global__ __launch_bounds__(256) void mfma_gemm2_k(
        const unsigned short* __restrict__ A, const unsigned short* __restrict__ Wf,
        const float* __restrict__ b2, unsigned short* __restrict__ y,
        float* __restrict__ out) {
    int wv = threadIdx.x >> 6, lane = threadIdx.x & 63;
    int m0 = blockIdx.x * 128 + wv * 32;
    int row = lane & 15, kg = lane >> 4;
    const short8* Wf8 = (const short8*)Wf;

    short8 af[2][8];
#pragma unroll
    for (int mt = 0; mt < 2; mt++) {
        const short8* ar = (const short8*)(A + (size_t)(m0 + mt * 16 + row) * 256 + kg * 8);
#pragma unroll
        for (int ks = 0; ks < 8; ks++) af[mt][ks] = ar[ks * 4];
    }
    f32x4 acc[2][8];
#pragma unroll
    for (int mt = 0; mt < 2; mt++)
#pragma unroll
        for (int nt = 0; nt < 8; nt++) acc[mt][nt] = (f32x4)(0.f);

#pragma unroll
    for (int ks = 0; ks < 8; ks++) {
        short8 bf[8];
#pragma unroll
        for (int nt = 0; nt < 8; nt++)
            bf[nt] = Wf8[(ks * 8 + nt) * 64 + lane];
#pragma unroll
        for (int nt = 0; nt < 8; nt++) {
#pragma unroll
            for (int mt = 0; mt < 2; mt++)
                acc[mt][nt] = __builtin_amdgcn_mfma_f32_16x16x32_bf16(af[mt][ks], bf[nt],
                                                                      acc[mt][nt], 0, 0, 0);
        }
    }

#pragma unroll
    for (int mt = 0; mt < 2; mt++) {
        int r0 = m0 + mt * 16 + kg * 4;
#pragma unroll
        for (int nt = 0; nt < 8; nt++) {
            int c = nt * 16 + row;   // 0..127
#pragma unroll
            for (int i = 0; i < 4; i++) {
                int rr = r0 + i;
                if (nt < 4) {
                    y[(size_t)rr * OUT_F + c] = f2bf(acc[mt][nt][i]);
                } else if (rr < N_NODES) {
                    out[(size_t)rr * OUT_F + (c - 64)] = acc[mt][nt][i] + b2[c - 64];
                }
            }
        }
    }
}

// ---------------- gather-mean layer 2: out[n] += mean y[src], 64 bf16 feats ----------------
__global__ void gather2_k(const unsigned short* __restrict__ y, const int* __restrict__ eids,
                          const int* __restrict__ rowptr, float* __restrict__ out) {
    int w = threadIdx.x >> 6, lane = threadIdx.x & 63;
    int node = blockIdx.x * 4 + w;
    if (node >= N_NODES) return;
    int b = rowptr[node], e = rowptr[node + 1];
    int half = lane >> 5, c2 = lane & 31;
    float a0 = 0.f, a1 = 0.f;
    for (int i = b + half; i < e; i += 2) {
        int s = eids[i];
        unsigned u = ((const unsigned*)(y + (size_t)s * OUT_F))[c2];
        a0 += __uint_as_float(u << 16);
        a1 += __uint_as_float(u & 0xffff0000u);
    }
    a0 += __shfl_xor(a0, 32);
    a1 += __shfl_xor(a1, 32);
    if (half == 0) {
        int deg = e - b; if (deg < 1) deg = 1;
        float inv = 1.f / (float)deg;
        float2* p = (float2*)(out + (size_t)node * OUT_F + 2 * c2);
        float2 cur = *p;
        cur.x += a0 * inv; cur.y += a1 * inv;
        *p = cur;
    }
}

extern "C" void kernel_launch(void* const* d_in, const int* in_sizes, int n_in,
                              void* d_out, int out_size, void* d_ws, size_t ws_size,
                              hipStream_t stream) {
    const float* x    = (const float*)d_in[0];
    const int*   eidx = (const int*)d_in[1];
    const float* W1l  = (const float*)d_in[2];
    const float* W1r  = (const float*)d_in[3];
    const float* b1   = (const float*)d_in[4];
    const float* W2l  = (const float*)d_in[5];
    const float* W2r  = (const float*)d_in[6];
    const float* b2   = (const float*)d_in[7];
    float* out = (float*)d_out;

    const int* src = eidx;             // edge_index[0]
    const int* dst = eidx + N_EDGES;   // edge_index[1]

    // workspace layout (ushort units)
    unsigned short* A1   = (unsigned short*)d_ws;              // [M_PAD][256] bf16
    unsigned short* hbuf = A1 + (size_t)M_PAD * 256;           // [M_PAD][256] bf16
    unsigned short* ybuf = hbuf + (size_t)M_PAD * 256;         // [M_PAD][64]  bf16
    unsigned short* W1f  = ybuf + (size_t)M_PAD * OUT_F;       // 65536 (frag layout)
    unsigned short* W2f  = W1f + 65536;                        // 32768 (frag layout)
    int* cnt    = (int*)(W2f + 32768);
    int* fill   = cnt + N_NODES;
    int* rowptr = fill + N_NODES;
    int* eids   = rowptr + N_NODES + 1;

    hipMemsetAsync(cnt, 0, (size_t)N_NODES * sizeof(int), stream);
    hipMemsetAsync(fill, 0, (size_t)N_NODES * sizeof(int), stream);

    // conversions (x -> bf16, weights -> MFMA fragment layout)
    convert_x_k<<<(N_NODES * 64 + 255) / 256, 256, 0, stream>>>(x, (unsigned int*)A1);
    convert_w1_k<<<128, 256, 0, stream>>>(W1l, W1r, (unsigned int*)W1f);
    convert_w2_k<<<64, 256, 0, stream>>>(W2l, W2r, (unsigned int*)W2f);

    // CSR build
    count_edges_k<<<(N_EDGES + 255) / 256, 256, 0, stream>>>(dst, cnt);
    scan_k<<<1, 1024, 0, stream>>>(cnt, rowptr);
    fill_k<<<(N_EDGES + 255) / 256, 256, 0, stream>>>(src, dst, rowptr, fill, eids);

    // layer-1 aggregation (gather-mean, bf16)
    gather1_k<<<(N_NODES + 3) / 4, 256, 0, stream>>>((const unsigned int*)A1, eids, rowptr,
                                                     (unsigned int*)A1);

    // GEMM1 -> h (bf16)
    mfma_gemm1_k<<<M_PAD / 64, 256, 0, stream>>>(A1, W1f, b1, hbuf);

    // GEMM2 -> y (bf16), out_r + b2 (fp32)
    mfma_gemm2_k<<<M_PAD / 128, 256, 0, stream>>>(hbuf, W2f, b2, ybuf, out);

    // layer-2 aggregation
    gather2_k<<<(N_NODES + 3) / 4, 256, 0, stream>>>(ybuf, eids, rowptr, out);
}

// Round 5
// 275.652 us; speedup vs baseline: 4.8983x; 1.2242x over previous
//
#include <hip/hip_runtime.h>
#include <hip/hip_bf16.h>

#define N_NODES 50000
#define N_EDGES 800000
#define IN_FEAT 128
#define HIDDEN  256
#define OUT_F   64
#define M_PAD   50048   // 782 * 64

typedef __attribute__((ext_vector_type(8))) short short8;
typedef __attribute__((ext_vector_type(4))) float f32x4;

static __device__ __forceinline__ unsigned short f2bf(float f) {
    unsigned u = __float_as_uint(f);
    unsigned r = (u + 0x7fffu + ((u >> 16) & 1u)) >> 16;   // RNE
    return (unsigned short)r;
}
static __device__ __forceinline__ float bflo(unsigned u) { return __uint_as_float(u << 16); }
static __device__ __forceinline__ float bfhi(unsigned u) { return __uint_as_float(u & 0xffff0000u); }

// ---------------- degree count ----------------
__global__ void count_edges_k(const int* __restrict__ dst, int* __restrict__ cnt) {
    int e = blockIdx.x * blockDim.x + threadIdx.x;
    if (e < N_EDGES) atomicAdd(&cnt[dst[e]], 1);
}

// ---------------- single-block exclusive scan over cnt -> rowptr ----------------
__global__ __launch_bounds__(1024) void scan_k(const int* __restrict__ cnt,
                                               int* __restrict__ rowptr) {
    __shared__ int part[1024];
    int t = threadIdx.x;
    const int CH = (N_NODES + 1023) / 1024;   // 49
    int begin = t * CH;
    int end = begin + CH; if (end > N_NODES) end = N_NODES;
    int s = 0;
    for (int i = begin; i < end && i < N_NODES; i++) s += cnt[i];
    part[t] = s;
    __syncthreads();
    for (int off = 1; off < 1024; off <<= 1) {
        int add = (t >= off) ? part[t - off] : 0;
        __syncthreads();
        part[t] += add;
        __syncthreads();
    }
    int run = (t == 0) ? 0 : part[t - 1];
    for (int i = begin; i < end && i < N_NODES; i++) { rowptr[i] = run; run += cnt[i]; }
    if (t == 1023) rowptr[N_NODES] = part[1023];
}

// ---------------- CSR fill ----------------
__global__ void fill_k(const int* __restrict__ src, const int* __restrict__ dst,
                       const int* __restrict__ rowptr, int* __restrict__ fill,
                       int* __restrict__ eids) {
    int e = blockIdx.x * blockDim.x + threadIdx.x;
    if (e < N_EDGES) {
        int d = dst[e];
        int pos = rowptr[d] + atomicAdd(&fill[d], 1);
        eids[pos] = src[e];
    }
}

// ---------------- convert x -> bf16 into A1[:,128:256] ----------------
__global__ void convert_x_k(const float* __restrict__ x, unsigned int* __restrict__ A1u) {
    int i = blockIdx.x * blockDim.x + threadIdx.x;   // pair index
    if (i >= N_NODES * 64) return;
    int n = i >> 6, p = i & 63;
    float2 v = ((const float2*)(x + (size_t)n * IN_FEAT))[p];
    A1u[(size_t)n * 128 + 64 + p] = (unsigned)f2bf(v.x) | ((unsigned)f2bf(v.y) << 16);
}

// ---------------- W1 -> MFMA fragment layout Wf1[ks][nt][lane][8] (bf16) ----------------
// fragment element: n = nt*16 + (lane&15), k = ks*32 + (lane>>4)*8 + j
// k<128 -> W1l (agg part), k>=128 -> W1r (x part)
__global__ void convert_w1_k(const float* __restrict__ W1l, const float* __restrict__ W1r,
                             unsigned int* __restrict__ Wf) {
    int i = blockIdx.x * blockDim.x + threadIdx.x;   // 32768 u32
    if (i >= 32768) return;
    int s = i * 2;
    int j = s & 7, lane = (s >> 3) & 63, nt = (s >> 9) & 15, ks = s >> 13;
    int n = nt * 16 + (lane & 15);
    int k = ks * 32 + ((lane >> 4) << 3) + j;
    float v0, v1;
    if (k < 128) { v0 = W1l[n * 128 + k];       v1 = W1l[n * 128 + k + 1]; }
    else         { v0 = W1r[n * 128 + k - 128]; v1 = W1r[n * 128 + k - 127]; }
    Wf[i] = (unsigned)f2bf(v0) | ((unsigned)f2bf(v1) << 16);
}

// ---------------- W2 -> fragment layout Wf2[ks][nt][lane][8]; n<64 -> W2l, else W2r ----------------
__global__ void convert_w2_k(const float* __restrict__ W2l, const float* __restrict__ W2r,
                             unsigned int* __restrict__ Wf) {
    int i = blockIdx.x * blockDim.x + threadIdx.x;   // 16384 u32
    if (i >= 16384) return;
    int s = i * 2;
    int j = s & 7, lane = (s >> 3) & 63, nt = (s >> 9) & 7, ks = s >> 12;
    int n = nt * 16 + (lane & 15);
    int k = ks * 32 + ((lane >> 4) << 3) + j;
    float v0, v1;
    if (n < 64) { v0 = W2l[n * 256 + k];        v1 = W2l[n * 256 + k + 1]; }
    else        { v0 = W2r[(n - 64) * 256 + k]; v1 = W2r[(n - 64) * 256 + k + 1]; }
    Wf[i] = (unsigned)f2bf(v0) | ((unsigned)f2bf(v1) << 16);
}

// ---------------- gather-mean layer 1: 4 edges/iter, dwordx4 per lane ----------------
// wave per node; lane = (edge-group eg=lane>>4, 16B-chunk cq=lane&15)
__global__ void gather1_k(const unsigned int* __restrict__ Au, const int* __restrict__ eids,
                          const int* __restrict__ rowptr, unsigned int* __restrict__ Aw) {
    int w = threadIdx.x >> 6, lane = threadIdx.x & 63;
    int node = blockIdx.x * 4 + w;
    if (node >= N_NODES) return;
    int b = rowptr[node], e = rowptr[node + 1];
    int eg = lane >> 4, cq = lane & 15;
    float a0 = 0.f, a1 = 0.f, a2 = 0.f, a3 = 0.f, a4 = 0.f, a5 = 0.f, a6 = 0.f, a7 = 0.f;
    for (int i = b + eg; i < e; i += 4) {
        int s = eids[i];
        uint4 v = ((const uint4*)(Au + (size_t)s * 128 + 64))[cq];
        a0 += bflo(v.x); a1 += bfhi(v.x);
        a2 += bflo(v.y); a3 += bfhi(v.y);
        a4 += bflo(v.z); a5 += bfhi(v.z);
        a6 += bflo(v.w); a7 += bfhi(v.w);
    }
#pragma unroll
    for (int m = 16; m <= 32; m <<= 1) {
        a0 += __shfl_xor(a0, m); a1 += __shfl_xor(a1, m);
        a2 += __shfl_xor(a2, m); a3 += __shfl_xor(a3, m);
        a4 += __shfl_xor(a4, m); a5 += __shfl_xor(a5, m);
        a6 += __shfl_xor(a6, m); a7 += __shfl_xor(a7, m);
    }
    if (eg == 0) {
        int deg = e - b; if (deg < 1) deg = 1;
        float inv = 1.f / (float)deg;
        uint4 r;
        r.x = (unsigned)f2bf(a0 * inv) | ((unsigned)f2bf(a1 * inv) << 16);
        r.y = (unsigned)f2bf(a2 * inv) | ((unsigned)f2bf(a3 * inv) << 16);
        r.z = (unsigned)f2bf(a4 * inv) | ((unsigned)f2bf(a5 * inv) << 16);
        r.w = (unsigned)f2bf(a6 * inv) | ((unsigned)f2bf(a7 * inv) << 16);
        ((uint4*)(Aw + (size_t)node * 128))[cq] = r;
    }
}

// ---------------- MFMA GEMM1: h = relu(A1 @ W1cat^T + b1), M=M_PAD N=256 K=256 ----------------
__global__ __launch_bounds__(256) void mfma_gemm1_k(
        const unsigned short* __restrict__ A, const unsigned short* __restrict__ Wf,
        const float* __restrict__ b1, unsigned short* __restrict__ h) {
    int wv = threadIdx.x >> 6, lane = threadIdx.x & 63;
    int rowh = wv >> 1, colh = wv & 1;
    int m0 = blockIdx.x * 64 + rowh * 32;
    int row = lane & 15, kg = lane >> 4;
    const short8* Wf8 = (const short8*)Wf;

    short8 af[2][8];
#pragma unroll
    for (int mt = 0; mt < 2; mt++) {
        const short8* ar = (const short8*)(A + (size_t)(m0 + mt * 16 + row) * 256 + kg * 8);
#pragma unroll
        for (int ks = 0; ks < 8; ks++) af[mt][ks] = ar[ks * 4];
    }
    f32x4 acc[2][8];
#pragma unroll
    for (int mt = 0; mt < 2; mt++)
#pragma unroll
        for (int nt = 0; nt < 8; nt++) acc[mt][nt] = (f32x4)(0.f);

#pragma unroll
    for (int ks = 0; ks < 8; ks++) {
        short8 bf[8];
#pragma unroll
        for (int nt = 0; nt < 8; nt++)
            bf[nt] = Wf8[(ks * 16 + colh * 8 + nt) * 64 + lane];
#pragma unroll
        for (int nt = 0; nt < 8; nt++) {
#pragma unroll
            for (int mt = 0; mt < 2; mt++)
                acc[mt][nt] = __builtin_amdgcn_mfma_f32_16x16x32_bf16(af[mt][ks], bf[nt],
                                                                      acc[mt][nt], 0, 0, 0);
        }
    }

#pragma unroll
    for (int mt = 0; mt < 2; mt++) {
        int r0 = m0 + mt * 16 + kg * 4;
#pragma unroll
        for (int nt = 0; nt < 8; nt++) {
            int c = colh * 128 + nt * 16 + row;
            float bias = b1[c];
#pragma unroll
            for (int i = 0; i < 4; i++) {
                float v = acc[mt][nt][i] + bias;
                v = v > 0.f ? v : 0.f;
                h[(size_t)(r0 + i) * 256 + c] = f2bf(v);
            }
        }
    }
}

// ---------------- MFMA GEMM2: [y | out_r] = h @ W2cat^T, M=M_PAD N=128 K=256 ----------------
__global__ __launch_bounds__(256) void mfma_gemm2_k(
        const unsigned short* __restrict__ A, const unsigned short* __restrict__ Wf,
        const float* __restrict__ b2, unsigned short* __restrict__ y,
        float* __restrict__ out) {
    int wv = threadIdx.x >> 6, lane = threadIdx.x & 63;
    int m0 = blockIdx.x * 128 + wv * 32;
    int row = lane & 15, kg = lane >> 4;
    const short8* Wf8 = (const short8*)Wf;

    short8 af[2][8];
#pragma unroll
    for (int mt = 0; mt < 2; mt++) {
        const short8* ar = (const short8*)(A + (size_t)(m0 + mt * 16 + row) * 256 + kg * 8);
#pragma unroll
        for (int ks = 0; ks < 8; ks++) af[mt][ks] = ar[ks * 4];
    }
    f32x4 acc[2][8];
#pragma unroll
    for (int mt = 0; mt < 2; mt++)
#pragma unroll
        for (int nt = 0; nt < 8; nt++) acc[mt][nt] = (f32x4)(0.f);

#pragma unroll
    for (int ks = 0; ks < 8; ks++) {
        short8 bf[8];
#pragma unroll
        for (int nt = 0; nt < 8; nt++)
            bf[nt] = Wf8[(ks * 8 + nt) * 64 + lane];
#pragma unroll
        for (int nt = 0; nt < 8; nt++) {
#pragma unroll
            for (int mt = 0; mt < 2; mt++)
                acc[mt][nt] = __builtin_amdgcn_mfma_f32_16x16x32_bf16(af[mt][ks], bf[nt],
                                                                      acc[mt][nt], 0, 0, 0);
        }
    }

#pragma unroll
    for (int mt = 0; mt < 2; mt++) {
        int r0 = m0 + mt * 16 + kg * 4;
#pragma unroll
        for (int nt = 0; nt < 8; nt++) {
            int c = nt * 16 + row;   // 0..127
#pragma unroll
            for (int i = 0; i < 4; i++) {
                int rr = r0 + i;
                if (nt < 4) {
                    y[(size_t)rr * OUT_F + c] = f2bf(acc[mt][nt][i]);
                } else if (rr < N_NODES) {
                    out[(size_t)rr * OUT_F + (c - 64)] = acc[mt][nt][i] + b2[c - 64];
                }
            }
        }
    }
}

// ---------------- gather-mean layer 2: 8 edges/iter, dwordx4 per lane ----------------
// wave per node; lane = (edge-group eg=lane>>3, 16B-chunk cq=lane&7)
__global__ void gather2_k(const unsigned int* __restrict__ yu, const int* __restrict__ eids,
                          const int* __restrict__ rowptr, float* __restrict__ out) {
    int w = threadIdx.x >> 6, lane = threadIdx.x & 63;
    int node = blockIdx.x * 4 + w;
    if (node >= N_NODES) return;
    int b = rowptr[node], e = rowptr[node + 1];
    int eg = lane >> 3, cq = lane & 7;
    float a0 = 0.f, a1 = 0.f, a2 = 0.f, a3 = 0.f, a4 = 0.f, a5 = 0.f, a6 = 0.f, a7 = 0.f;
    for (int i = b + eg; i < e; i += 8) {
        int s = eids[i];
        uint4 v = ((const uint4*)(yu + (size_t)s * 32))[cq];
        a0 += bflo(v.x); a1 += bfhi(v.x);
        a2 += bflo(v.y); a3 += bfhi(v.y);
        a4 += bflo(v.z); a5 += bfhi(v.z);
        a6 += bflo(v.w); a7 += bfhi(v.w);
    }
#pragma unroll
    for (int m = 8; m <= 32; m <<= 1) {
        a0 += __shfl_xor(a0, m); a1 += __shfl_xor(a1, m);
        a2 += __shfl_xor(a2, m); a3 += __shfl_xor(a3, m);
        a4 += __shfl_xor(a4, m); a5 += __shfl_xor(a5, m);
        a6 += __shfl_xor(a6, m); a7 += __shfl_xor(a7, m);
    }
    if (eg == 0) {
        int deg = e - b; if (deg < 1) deg = 1;
        float inv = 1.f / (float)deg;
        float4* p = (float4*)(out + (size_t)node * OUT_F + cq * 8);
        float4 c0 = p[0], c1 = p[1];
        c0.x += a0 * inv; c0.y += a1 * inv; c0.z += a2 * inv; c0.w += a3 * inv;
        c1.x += a4 * inv; c1.y += a5 * inv; c1.z += a6 * inv; c1.w += a7 * inv;
        p[0] = c0; p[1] = c1;
    }
}

extern "C" void kernel_launch(void* const* d_in, const int* in_sizes, int n_in,
                              void* d_out, int out_size, void* d_ws, size_t ws_size,
                              hipStream_t stream) {
    const float* x    = (const float*)d_in[0];
    const int*   eidx = (const int*)d_in[1];
    const float* W1l  = (const float*)d_in[2];
    const float* W1r  = (const float*)d_in[3];
    const float* b1   = (const float*)d_in[4];
    const float* W2l  = (const float*)d_in[5];
    const float* W2r  = (const float*)d_in[6];
    const float* b2   = (const float*)d_in[7];
    float* out = (float*)d_out;

    const int* src = eidx;             // edge_index[0]
    const int* dst = eidx + N_EDGES;   // edge_index[1]

    // workspace layout (ushort units)
    unsigned short* A1   = (unsigned short*)d_ws;              // [M_PAD][256] bf16
    unsigned short* hbuf = A1 + (size_t)M_PAD * 256;           // [M_PAD][256] bf16
    unsigned short* ybuf = hbuf + (size_t)M_PAD * 256;         // [M_PAD][64]  bf16
    unsigned short* W1f  = ybuf + (size_t)M_PAD * OUT_F;       // 65536 (frag layout)
    unsigned short* W2f  = W1f + 65536;                        // 32768 (frag layout)
    int* cnt    = (int*)(W2f + 32768);
    int* fill   = cnt + N_NODES;
    int* rowptr = fill + N_NODES;
    int* eids   = rowptr + N_NODES + 1;

    hipMemsetAsync(cnt, 0, (size_t)N_NODES * sizeof(int), stream);
    hipMemsetAsync(fill, 0, (size_t)N_NODES * sizeof(int), stream);

    // conversions (x -> bf16, weights -> MFMA fragment layout)
    convert_x_k<<<(N_NODES * 64 + 255) / 256, 256, 0, stream>>>(x, (unsigned int*)A1);
    convert_w1_k<<<128, 256, 0, stream>>>(W1l, W1r, (unsigned int*)W1f);
    convert_w2_k<<<64, 256, 0, stream>>>(W2l, W2r, (unsigned int*)W2f);

    // CSR build
    count_edges_k<<<(N_EDGES + 255) / 256, 256, 0, stream>>>(dst, cnt);
    scan_k<<<1, 1024, 0, stream>>>(cnt, rowptr);
    fill_k<<<(N_EDGES + 255) / 256, 256, 0, stream>>>(src, dst, rowptr, fill, eids);

    // layer-1 aggregation (gather-mean, 4 edges/iter)
    gather1_k<<<(N_NODES + 3) / 4, 256, 0, stream>>>((const unsigned int*)A1, eids, rowptr,
                                                     (unsigned int*)A1);

    // GEMM1 -> h (bf16)
    mfma_gemm1_k<<<M_PAD / 64, 256, 0, stream>>>(A1, W1f, b1, hbuf);

    // GEMM2 -> y (bf16), out_r + b2 (fp32)
    mfma_gemm2_k<<<M_PAD / 128, 256, 0, stream>>>(hbuf, W2f, b2, ybuf, out);

    // layer-2 aggregation (gather-mean, 8 edges/iter)
    gather2_k<<<(N_NODES + 3) / 4, 256, 0, stream>>>((const unsigned int*)ybuf, eids, rowptr, out);
}

// Round 6
// 207.312 us; speedup vs baseline: 6.5130x; 1.3296x over previous
//
#include <hip/hip_runtime.h>
#include <hip/hip_bf16.h>

#define N_NODES 50000
#define N_EDGES 800000
#define IN_FEAT 128
#define HIDDEN  256
#define OUT_F   64
#define M_PAD   50048   // 782 * 64
#define SCAN_NB 196     // ceil(N_NODES / 256)

typedef __attribute__((ext_vector_type(8))) short short8;
typedef __attribute__((ext_vector_type(4))) float f32x4;

static __device__ __forceinline__ unsigned short f2bf(float f) {
    unsigned u = __float_as_uint(f);
    unsigned r = (u + 0x7fffu + ((u >> 16) & 1u)) >> 16;   // RNE
    return (unsigned short)r;
}
static __device__ __forceinline__ float bflo(unsigned u) { return __uint_as_float(u << 16); }
static __device__ __forceinline__ float bfhi(unsigned u) { return __uint_as_float(u & 0xffff0000u); }

// ---------------- degree count ----------------
__global__ void count_edges_k(const int* __restrict__ dst, int* __restrict__ cnt) {
    int e = blockIdx.x * blockDim.x + threadIdx.x;
    if (e < N_EDGES) atomicAdd(&cnt[dst[e]], 1);
}

// ---------------- scan phase A: per-block sums of cnt ----------------
__global__ __launch_bounds__(256) void bsum_k(const int* __restrict__ cnt,
                                              int* __restrict__ bsum) {
    int i = blockIdx.x * 256 + threadIdx.x;
    int v = (i < N_NODES) ? cnt[i] : 0;
#pragma unroll
    for (int m = 1; m < 64; m <<= 1) v += __shfl_xor(v, m);
    __shared__ int ws4[4];
    if ((threadIdx.x & 63) == 0) ws4[threadIdx.x >> 6] = v;
    __syncthreads();
    if (threadIdx.x == 0) bsum[blockIdx.x] = ws4[0] + ws4[1] + ws4[2] + ws4[3];
}

// ---------------- scan phase B: exclusive scan of block sums (1 block) ----------------
__global__ __launch_bounds__(256) void bscan_k(const int* __restrict__ bsum,
                                               int* __restrict__ boff) {
    __shared__ int s[256];
    int t = threadIdx.x;
    int v = (t < SCAN_NB) ? bsum[t] : 0;
    s[t] = v;
    __syncthreads();
    for (int off = 1; off < 256; off <<= 1) {
        int add = (t >= off) ? s[t - off] : 0;
        __syncthreads();
        s[t] += add;
        __syncthreads();
    }
    if (t < SCAN_NB) boff[t] = s[t] - v;   // exclusive
}

// ---------------- scan phase C: per-block exclusive scan + offset -> rowptr ----------------
__global__ __launch_bounds__(256) void rowptr_k(const int* __restrict__ cnt,
                                                const int* __restrict__ boff,
                                                int* __restrict__ rowptr) {
    __shared__ int s[256];
    int t = threadIdx.x;
    int i = blockIdx.x * 256 + t;
    int v = (i < N_NODES) ? cnt[i] : 0;
    s[t] = v;
    __syncthreads();
    for (int off = 1; off < 256; off <<= 1) {
        int add = (t >= off) ? s[t - off] : 0;
        __syncthreads();
        s[t] += add;
        __syncthreads();
    }
    if (i < N_NODES) rowptr[i] = boff[blockIdx.x] + s[t] - v;
    if (blockIdx.x == 0 && t == 0) rowptr[N_NODES] = N_EDGES;
}

// ---------------- CSR fill ----------------
__global__ void fill_k(const int* __restrict__ src, const int* __restrict__ dst,
                       const int* __restrict__ rowptr, int* __restrict__ fill,
                       int* __restrict__ eids) {
    int e = blockIdx.x * blockDim.x + threadIdx.x;
    if (e < N_EDGES) {
        int d = dst[e];
        int pos = rowptr[d] + atomicAdd(&fill[d], 1);
        eids[pos] = src[e];
    }
}

// ---------------- convert x -> bf16 into A1[:,128:256] ----------------
__global__ void convert_x_k(const float* __restrict__ x, unsigned int* __restrict__ A1u) {
    int i = blockIdx.x * blockDim.x + threadIdx.x;   // pair index
    if (i >= N_NODES * 64) return;
    int n = i >> 6, p = i & 63;
    float2 v = ((const float2*)(x + (size_t)n * IN_FEAT))[p];
    A1u[(size_t)n * 128 + 64 + p] = (unsigned)f2bf(v.x) | ((unsigned)f2bf(v.y) << 16);
}

// ---------------- W1 -> MFMA fragment layout Wf1[ks][nt][lane][8] (bf16) ----------------
__global__ void convert_w1_k(const float* __restrict__ W1l, const float* __restrict__ W1r,
                             unsigned int* __restrict__ Wf) {
    int i = blockIdx.x * blockDim.x + threadIdx.x;   // 32768 u32
    if (i >= 32768) return;
    int s = i * 2;
    int j = s & 7, lane = (s >> 3) & 63, nt = (s >> 9) & 15, ks = s >> 13;
    int n = nt * 16 + (lane & 15);
    int k = ks * 32 + ((lane >> 4) << 3) + j;
    float v0, v1;
    if (k < 128) { v0 = W1l[n * 128 + k];       v1 = W1l[n * 128 + k + 1]; }
    else         { v0 = W1r[n * 128 + k - 128]; v1 = W1r[n * 128 + k - 127]; }
    Wf[i] = (unsigned)f2bf(v0) | ((unsigned)f2bf(v1) << 16);
}

// ---------------- W2 -> fragment layout Wf2[ks][nt][lane][8] ----------------
__global__ void convert_w2_k(const float* __restrict__ W2l, const float* __restrict__ W2r,
                             unsigned int* __restrict__ Wf) {
    int i = blockIdx.x * blockDim.x + threadIdx.x;   // 16384 u32
    if (i >= 16384) return;
    int s = i * 2;
    int j = s & 7, lane = (s >> 3) & 63, nt = (s >> 9) & 7, ks = s >> 12;
    int n = nt * 16 + (lane & 15);
    int k = ks * 32 + ((lane >> 4) << 3) + j;
    float v0, v1;
    if (n < 64) { v0 = W2l[n * 256 + k];        v1 = W2l[n * 256 + k + 1]; }
    else        { v0 = W2r[(n - 64) * 256 + k]; v1 = W2r[(n - 64) * 256 + k + 1]; }
    Wf[i] = (unsigned)f2bf(v0) | ((unsigned)f2bf(v1) << 16);
}

// ---------------- gather-mean layer 1: 4 edges/iter, dwordx4 per lane ----------------
__global__ void gather1_k(const unsigned int* __restrict__ Au, const int* __restrict__ eids,
                          const int* __restrict__ rowptr, unsigned int* __restrict__ Aw) {
    int w = threadIdx.x >> 6, lane = threadIdx.x & 63;
    int node = blockIdx.x * 4 + w;
    if (node >= N_NODES) return;
    int b = rowptr[node], e = rowptr[node + 1];
    int eg = lane >> 4, cq = lane & 15;
    float a0 = 0.f, a1 = 0.f, a2 = 0.f, a3 = 0.f, a4 = 0.f, a5 = 0.f, a6 = 0.f, a7 = 0.f;
    for (int i = b + eg; i < e; i += 4) {
        int s = eids[i];
        uint4 v = ((const uint4*)(Au + (size_t)s * 128 + 64))[cq];
        a0 += bflo(v.x); a1 += bfhi(v.x);
        a2 += bflo(v.y); a3 += bfhi(v.y);
        a4 += bflo(v.z); a5 += bfhi(v.z);
        a6 += bflo(v.w); a7 += bfhi(v.w);
    }
#pragma unroll
    for (int m = 16; m <= 32; m <<= 1) {
        a0 += __shfl_xor(a0, m); a1 += __shfl_xor(a1, m);
        a2 += __shfl_xor(a2, m); a3 += __shfl_xor(a3, m);
        a4 += __shfl_xor(a4, m); a5 += __shfl_xor(a5, m);
        a6 += __shfl_xor(a6, m); a7 += __shfl_xor(a7, m);
    }
    if (eg == 0) {
        int deg = e - b; if (deg < 1) deg = 1;
        float inv = 1.f / (float)deg;
        uint4 r;
        r.x = (unsigned)f2bf(a0 * inv) | ((unsigned)f2bf(a1 * inv) << 16);
        r.y = (unsigned)f2bf(a2 * inv) | ((unsigned)f2bf(a3 * inv) << 16);
        r.z = (unsigned)f2bf(a4 * inv) | ((unsigned)f2bf(a5 * inv) << 16);
        r.w = (unsigned)f2bf(a6 * inv) | ((unsigned)f2bf(a7 * inv) << 16);
        ((uint4*)(Aw + (size_t)node * 128))[cq] = r;
    }
}

// ---------------- MFMA GEMM1: h = relu(A1 @ W1cat^T + b1), M=M_PAD N=256 K=256 ----------------
__global__ __launch_bounds__(256) void mfma_gemm1_k(
        const unsigned short* __restrict__ A, const unsigned short* __restrict__ Wf,
        const float* __restrict__ b1, unsigned short* __restrict__ h) {
    int wv = threadIdx.x >> 6, lane = threadIdx.x & 63;
    int rowh = wv >> 1, colh = wv & 1;
    int m0 = blockIdx.x * 64 + rowh * 32;
    int row = lane & 15, kg = lane >> 4;
    const short8* Wf8 = (const short8*)Wf;

    short8 af[2][8];
#pragma unroll
    for (int mt = 0; mt < 2; mt++) {
        const short8* ar = (const short8*)(A + (size_t)(m0 + mt * 16 + row) * 256 + kg * 8);
#pragma unroll
        for (int ks = 0; ks < 8; ks++) af[mt][ks] = ar[ks * 4];
    }
    f32x4 acc[2][8];
#pragma unroll
    for (int mt = 0; mt < 2; mt++)
#pragma unroll
        for (int nt = 0; nt < 8; nt++) acc[mt][nt] = (f32x4)(0.f);

#pragma unroll
    for (int ks = 0; ks < 8; ks++) {
        short8 bf[8];
#pragma unroll
        for (int nt = 0; nt < 8; nt++)
            bf[nt] = Wf8[(ks * 16 + colh * 8 + nt) * 64 + lane];
#pragma unroll
        for (int nt = 0; nt < 8; nt++) {
#pragma unroll
            for (int mt = 0; mt < 2; mt++)
                acc[mt][nt] = __builtin_amdgcn_mfma_f32_16x16x32_bf16(af[mt][ks], bf[nt],
                                                                      acc[mt][nt], 0, 0, 0);
        }
    }

#pragma unroll
    for (int mt = 0; mt < 2; mt++) {
        int r0 = m0 + mt * 16 + kg * 4;
#pragma unroll
        for (int nt = 0; nt < 8; nt++) {
            int c = colh * 128 + nt * 16 + row;
            float bias = b1[c];
#pragma unroll
            for (int i = 0; i < 4; i++) {
                float v = acc[mt][nt][i] + bias;
                v = v > 0.f ? v : 0.f;
                h[(size_t)(r0 + i) * 256 + c] = f2bf(v);
            }
        }
    }
}

// ---------------- MFMA GEMM2: [y | out_r] = h @ W2cat^T, M=M_PAD N=128 K=256 ----------------
__global__ __launch_bounds__(256) void mfma_gemm2_k(
        const unsigned short* __restrict__ A, const unsigned short* __restrict__ Wf,
        const float* __restrict__ b2, unsigned short* __restrict__ y,
        float* __restrict__ out) {
    int wv = threadIdx.x >> 6, lane = threadIdx.x & 63;
    int m0 = blockIdx.x * 128 + wv * 32;
    int row = lane & 15, kg = lane >> 4;
    const short8* Wf8 = (const short8*)Wf;

    short8 af[2][8];
#pragma unroll
    for (int mt = 0; mt < 2; mt++) {
        const short8* ar = (const short8*)(A + (size_t)(m0 + mt * 16 + row) * 256 + kg * 8);
#pragma unroll
        for (int ks = 0; ks < 8; ks++) af[mt][ks] = ar[ks * 4];
    }
    f32x4 acc[2][8];
#pragma unroll
    for (int mt = 0; mt < 2; mt++)
#pragma unroll
        for (int nt = 0; nt < 8; nt++) acc[mt][nt] = (f32x4)(0.f);

#pragma unroll
    for (int ks = 0; ks < 8; ks++) {
        short8 bf[8];
#pragma unroll
        for (int nt = 0; nt < 8; nt++)
            bf[nt] = Wf8[(ks * 8 + nt) * 64 + lane];
#pragma unroll
        for (int nt = 0; nt < 8; nt++) {
#pragma unroll
            for (int mt = 0; mt < 2; mt++)
                acc[mt][nt] = __builtin_amdgcn_mfma_f32_16x16x32_bf16(af[mt][ks], bf[nt],
                                                                      acc[mt][nt], 0, 0, 0);
        }
    }

#pragma unroll
    for (int mt = 0; mt < 2; mt++) {
        int r0 = m0 + mt * 16 + kg * 4;
#pragma unroll
        for (int nt = 0; nt < 8; nt++) {
            int c = nt * 16 + row;   // 0..127
#pragma unroll
            for (int i = 0; i < 4; i++) {
                int rr = r0 + i;
                if (nt < 4) {
                    y[(size_t)rr * OUT_F + c] = f2bf(acc[mt][nt][i]);
                } else if (rr < N_NODES) {
                    out[(size_t)rr * OUT_F + (c - 64)] = acc[mt][nt][i] + b2[c - 64];
                }
            }
        }
    }
}

// ---------------- gather-mean layer 2: 8 edges/iter, dwordx4 per lane ----------------
__global__ void gather2_k(const unsigned int* __restrict__ yu, const int* __restrict__ eids,
                          const int* __restrict__ rowptr, float* __restrict__ out) {
    int w = threadIdx.x >> 6, lane = threadIdx.x & 63;
    int node = blockIdx.x * 4 + w;
    if (node >= N_NODES) return;
    int b = rowptr[node], e = rowptr[node + 1];
    int eg = lane >> 3, cq = lane & 7;
    float a0 = 0.f, a1 = 0.f, a2 = 0.f, a3 = 0.f, a4 = 0.f, a5 = 0.f, a6 = 0.f, a7 = 0.f;
    for (int i = b + eg; i < e; i += 8) {
        int s = eids[i];
        uint4 v = ((const uint4*)(yu + (size_t)s * 32))[cq];
        a0 += bflo(v.x); a1 += bfhi(v.x);
        a2 += bflo(v.y); a3 += bfhi(v.y);
        a4 += bflo(v.z); a5 += bfhi(v.z);
        a6 += bflo(v.w); a7 += bfhi(v.w);
    }
#pragma unroll
    for (int m = 8; m <= 32; m <<= 1) {
        a0 += __shfl_xor(a0, m); a1 += __shfl_xor(a1, m);
        a2 += __shfl_xor(a2, m); a3 += __shfl_xor(a3, m);
        a4 += __shfl_xor(a4, m); a5 += __shfl_xor(a5, m);
        a6 += __shfl_xor(a6, m); a7 += __shfl_xor(a7, m);
    }
    if (eg == 0) {
        int deg = e - b; if (deg < 1) deg = 1;
        float inv = 1.f / (float)deg;
        float4* p = (float4*)(out + (size_t)node * OUT_F + cq * 8);
        float4 c0 = p[0], c1 = p[1];
        c0.x += a0 * inv; c0.y += a1 * inv; c0.z += a2 * inv; c0.w += a3 * inv;
        c1.x += a4 * inv; c1.y += a5 * inv; c1.z += a6 * inv; c1.w += a7 * inv;
        p[0] = c0; p[1] = c1;
    }
}

extern "C" void kernel_launch(void* const* d_in, const int* in_sizes, int n_in,
                              void* d_out, int out_size, void* d_ws, size_t ws_size,
                              hipStream_t stream) {
    const float* x    = (const float*)d_in[0];
    const int*   eidx = (const int*)d_in[1];
    const float* W1l  = (const float*)d_in[2];
    const float* W1r  = (const float*)d_in[3];
    const float* b1   = (const float*)d_in[4];
    const float* W2l  = (const float*)d_in[5];
    const float* W2r  = (const float*)d_in[6];
    const float* b2   = (const float*)d_in[7];
    float* out = (float*)d_out;

    const int* src = eidx;             // edge_index[0]
    const int* dst = eidx + N_EDGES;   // edge_index[1]

    // workspace layout (ushort units)
    unsigned short* A1   = (unsigned short*)d_ws;              // [M_PAD][256] bf16
    unsigned short* hbuf = A1 + (size_t)M_PAD * 256;           // [M_PAD][256] bf16
    unsigned short* ybuf = hbuf + (size_t)M_PAD * 256;         // [M_PAD][64]  bf16
    unsigned short* W1f  = ybuf + (size_t)M_PAD * OUT_F;       // 65536 (frag layout)
    unsigned short* W2f  = W1f + 65536;                        // 32768 (frag layout)
    int* cnt    = (int*)(W2f + 32768);
    int* fill   = cnt + N_NODES;
    int* rowptr = fill + N_NODES;
    int* eids   = rowptr + N_NODES + 1;
    int* bsum   = eids + N_EDGES;
    int* boff   = bsum + SCAN_NB;

    hipMemsetAsync(cnt, 0, (size_t)N_NODES * sizeof(int), stream);
    hipMemsetAsync(fill, 0, (size_t)N_NODES * sizeof(int), stream);

    // conversions (x -> bf16, weights -> MFMA fragment layout)
    convert_x_k<<<(N_NODES * 64 + 255) / 256, 256, 0, stream>>>(x, (unsigned int*)A1);
    convert_w1_k<<<128, 256, 0, stream>>>(W1l, W1r, (unsigned int*)W1f);
    convert_w2_k<<<64, 256, 0, stream>>>(W2l, W2r, (unsigned int*)W2f);

    // CSR build (3-phase device-wide scan)
    count_edges_k<<<(N_EDGES + 255) / 256, 256, 0, stream>>>(dst, cnt);
    bsum_k<<<SCAN_NB, 256, 0, stream>>>(cnt, bsum);
    bscan_k<<<1, 256, 0, stream>>>(bsum, boff);
    rowptr_k<<<SCAN_NB, 256, 0, stream>>>(cnt, boff, rowptr);
    fill_k<<<(N_EDGES + 255) / 256, 256, 0, stream>>>(src, dst, rowptr, fill, eids);

    // layer-1 aggregation (gather-mean, 4 edges/iter)
    gather1_k<<<(N_NODES + 3) / 4, 256, 0, stream>>>((const unsigned int*)A1, eids, rowptr,
                                                     (unsigned int*)A1);

    // GEMM1 -> h (bf16)
    mfma_gemm1_k<<<M_PAD / 64, 256, 0, stream>>>(A1, W1f, b1, hbuf);

    // GEMM2 -> y (bf16), out_r + b2 (fp32)
    mfma_gemm2_k<<<M_PAD / 128, 256, 0, stream>>>(hbuf, W2f, b2, ybuf, out);

    // layer-2 aggregation (gather-mean, 8 edges/iter)
    gather2_k<<<(N_NODES + 3) / 4, 256, 0, stream>>>((const unsigned int*)ybuf, eids, rowptr, out);
}